// Round 7
// baseline (164.218 us; speedup 1.0000x reference)
//
#include <hip/hip_runtime.h>
#include <stdint.h>

// Head: x[8,2048,1024] fp32; Wk/Wq/Wv [1024,64] fp32 -> out [8,2048,64] fp32
// R14: qkv = R13 geometry (512 thr, 32x192 tile, same LDS layouts + frag
// formulas + epilogue) with the sync structure replaced: counted-vmcnt
// pipeline (T3+T4). R13 proved occupancy is NOT the lever (2x waves -> 40.8
// ->40.4us): the __syncthreads vmcnt(0) drain exposes the full staging
// round-trip EVERY chunk (~6000cyc/chunk vs ~400 compute). Here: 4 LDS
// buffers (128KB, m201-proven size), prologue stages chunks 0..2, each iter
// does s_waitcnt vmcnt(8) -> raw s_barrier -> stage chunk i+3 -> compute
// chunk i. Own-wave stages = exactly 4 VMEM ops/chunk, so vmcnt(8) retires
// chunk i while i+1,i+2 stay in flight; never drains to 0 until the tail.
// Each stage has 3 chunk-periods of slack. wconv + attn unchanged (R9).

#define B_ 8
#define T_ 2048
#define C_ 1024
#define H_ 64

typedef float f32x4 __attribute__((ext_vector_type(4)));
typedef short s16x8 __attribute__((ext_vector_type(8)));

__device__ __forceinline__ unsigned int rhu16(float f) {
    return (__float_as_uint(f) + 0x8000u) >> 16;
}
__device__ __forceinline__ unsigned int pkbf(float lo, float hi) {
    unsigned int a = __float_as_uint(lo) + 0x8000u;
    unsigned int b = __float_as_uint(hi) + 0x8000u;
    return __builtin_amdgcn_perm(b, a, 0x07060302u);   // bytes [b3 b2 a3 a2]
}
// async global->LDS, 16B per lane; LDS dest = wave-uniform base + lane*16
__device__ __forceinline__ void ld_lds16(const void* g, void* l) {
    __builtin_amdgcn_global_load_lds(
        (const __attribute__((address_space(1))) unsigned int*)g,
        (__attribute__((address_space(3))) unsigned int*)l, 16, 0, 0);
}

// ---------------------------------------------------------------------------
// K0: 48 blocks = 3 mats x 16 c-groups of 64. Coalesced read, LDS transpose
// (stride 65), coalesced bf16 write. Wq pre-scaled by 1/32 (C^-0.5).
// ---------------------------------------------------------------------------
__global__ __launch_bounds__(256) void wconv(const float* __restrict__ Wk,
        const float* __restrict__ Wq, const float* __restrict__ Wv,
        unsigned short* __restrict__ Wt) {
    __shared__ float ls[64 * 65];
    const int bx = blockIdx.x, t = threadIdx.x;
    const int mat = bx >> 4, c0 = (bx & 15) << 6;
    const float* W = (mat == 0) ? Wk : ((mat == 1) ? Wq : Wv);
    const float sc = (mat == 1) ? 0.03125f : 1.0f;
    #pragma unroll
    for (int k = 0; k < 4; k++) {
        int i = t + (k << 8);
        int cr = i >> 4, hq = (i & 15) << 2;
        float4 v = *reinterpret_cast<const float4*>(&W[(size_t)(c0 + cr) * H_ + hq]);
        ls[cr * 65 + hq + 0] = v.x; ls[cr * 65 + hq + 1] = v.y;
        ls[cr * 65 + hq + 2] = v.z; ls[cr * 65 + hq + 3] = v.w;
    }
    __syncthreads();
    #pragma unroll
    for (int k = 0; k < 4; k++) {
        int i = t + (k << 8);
        int h = i >> 4, cq = (i & 15) << 2;
        float a = ls[(cq + 0) * 65 + h] * sc, b = ls[(cq + 1) * 65 + h] * sc;
        float c = ls[(cq + 2) * 65 + h] * sc, d = ls[(cq + 3) * 65 + h] * sc;
        uint2 o; o.x = pkbf(a, b); o.y = pkbf(c, d);
        *reinterpret_cast<uint2*>(&Wt[(size_t)(mat * 64 + h) * C_ + c0 + cq]) = o;
    }
}

// ---------------------------------------------------------------------------
// K1: QKV projection — counted-vmcnt pipelined staging. 512 blocks x 512
// thr; block = 32 rows x 192 cols; wave (wr=w>>2, colb=(w&3)*48) owns 16
// rows x 48 cols. Per chunk per wave: 4 global_load_lds (1 x + 3 W),
// ds_read frags, pack, 6 MFMA. 4 buffers x 32KB; depth-3 prefetch;
// s_waitcnt vmcnt(8) + raw s_barrier per chunk (drain only at tail).
// ---------------------------------------------------------------------------
__global__ __launch_bounds__(512) __attribute__((amdgpu_waves_per_eu(2)))
void qkv(const float* __restrict__ x,
        const unsigned short* __restrict__ Wt,
        unsigned short* __restrict__ kb, unsigned short* __restrict__ qb,
        unsigned short* __restrict__ vtb) {
    __shared__ __align__(16) char smem[131072];  // 4 bufs x (8KB x | 24KB W)
    const int t = threadIdx.x, lane = t & 63, w = t >> 6;   // w in 0..7
    const int l15 = lane & 15, quad = lane >> 4;
    const int bx = blockIdx.x;
    const int bb = bx >> 6;                 // batch
    const int mt = bx & 63;                 // 32-row tile within batch
    const int m0 = bb * T_ + mt * 32;
    const int wr = w >> 2;                  // row-half of the 32-row tile
    const int colb = (w & 3) * 48;          // 48-col strip

    // per-wave async shares: 1 x-instr (id = w), 3 W-instrs (g = w*3+n).
    // x LDS layout [rg][j][quad][l15] @ id*1024+lane*16 (id = rg*4+j);
    // W LDS layout [g][k8][col&7]    @ 8192 + g*1024+lane*16.
    size_t xg; int xl;
    {
        int rg = w >> 2, j = w & 3;
        xg = (size_t)(m0 + rg * 16 + l15) * C_ + j * 16 + quad * 4;
        xl = w * 1024 + lane * 16;
    }
    size_t wg[3]; int wl[3];
    #pragma unroll
    for (int n = 0; n < 3; n++) {
        int g = w * 3 + n;
        wg[n] = (size_t)(g * 8 + (lane & 7)) * C_ + (lane >> 3) * 8;
        wl[n] = 8192 + g * 1024 + lane * 16;
    }

    // prologue: stage chunks 0..2 into buffers 0..2 (12 VMEM ops in flight)
    #pragma unroll
    for (int c = 0; c < 3; c++) {
        char* cb = smem + c * 32768;
        const int k0 = c * 64;
        ld_lds16(x + xg + k0, cb + xl);
        #pragma unroll
        for (int n = 0; n < 3; n++) ld_lds16(Wt + wg[n] + k0, cb + wl[n]);
    }

    f32x4 acc[3];
    #pragma unroll
    for (int ct = 0; ct < 3; ct++)
        #pragma unroll
        for (int j = 0; j < 4; j++) acc[ct][j] = 0.0f;

    #pragma unroll
    for (int i = 0; i < 16; i++) {
        // retire chunk i's own 4 stages; keep i+1,i+2 (8 ops) in flight
        if (i < 14)       asm volatile("s_waitcnt vmcnt(8)" ::: "memory");
        else if (i == 14) asm volatile("s_waitcnt vmcnt(4)" ::: "memory");
        else              asm volatile("s_waitcnt vmcnt(0)" ::: "memory");
        __builtin_amdgcn_sched_barrier(0);
        __builtin_amdgcn_s_barrier();       // all waves' chunk-i stages done;
        __builtin_amdgcn_sched_barrier(0);  // buf (i-1)&3 fully consumed

        // stage chunk i+3 into buf (i+3)&3 (= (i-1)&3, WAR-safe post-barrier)
        if (i < 13) {
            const int k3 = (i + 3) * 64;
            char* nxt = smem + ((i + 3) & 3) * 32768;
            ld_lds16(x + xg + k3, nxt + xl);
            #pragma unroll
            for (int n = 0; n < 3; n++) ld_lds16(Wt + wg[n] + k3, nxt + wl[n]);
        }

        const char* cur = smem + (i & 3) * 32768;
        const float* xc = (const float*)cur;
        const unsigned short* wcp = (const unsigned short*)(cur + 8192);

        // frag reads from LDS (chunk i resident; no vmcnt dependence)
        float4 xr[2][2];
        #pragma unroll
        for (int ks = 0; ks < 2; ks++)
            #pragma unroll
            for (int h = 0; h < 2; h++) {
                int c = ks * 32 + quad * 8 + h * 4;
                int j = c >> 4, u = (c & 15) >> 2;
                xr[ks][h] = *reinterpret_cast<const float4*>(
                    xc + (wr * 4 + j) * 256 + u * 64 + l15 * 4);
            }
        s16x8 wfr[3][2];
        #pragma unroll
        for (int ct = 0; ct < 3; ct++)
            #pragma unroll
            for (int ks = 0; ks < 2; ks++) {
                int col = colb + ct * 16 + l15;
                wfr[ct][ks] = *reinterpret_cast<const s16x8*>(
                    wcp + (col >> 3) * 512 + ((4 * ks + quad) * 8 + (col & 7)) * 8);
            }

        // pack fp32 -> bf16 A-frags and MFMA
        s16x8 af[2];
        #pragma unroll
        for (int ks = 0; ks < 2; ks++) {
            const float4 a = xr[ks][0], b = xr[ks][1];
            uint4 pk;
            pk.x = pkbf(a.x, a.y); pk.y = pkbf(a.z, a.w);
            pk.z = pkbf(b.x, b.y); pk.w = pkbf(b.z, b.w);
            af[ks] = *reinterpret_cast<s16x8*>(&pk);
        }
        #pragma unroll
        for (int ks = 0; ks < 2; ks++)
            #pragma unroll
            for (int ct = 0; ct < 3; ct++)
                acc[ct] = __builtin_amdgcn_mfma_f32_16x16x32_bf16(
                    af[ks], wfr[ct][ks], acc[ct], 0, 0, 0);
    }

    // epilogue: C row = quad*4+reg (within wave's 16-row strip), col = l15
    #pragma unroll
    for (int ct = 0; ct < 3; ct++) {
        int cbv = colb + ct * 16;
        int sel = cbv >> 6;                 // 0=K 1=Q 2=V, wave-uniform
        int h = (cbv & 63) + l15;
        int row0 = m0 + wr * 16 + quad * 4;
        if (sel < 2) {
            unsigned short* dst = sel ? qb : kb;
            #pragma unroll
            for (int r = 0; r < 4; r++)
                dst[(size_t)(row0 + r) * H_ + h] = (unsigned short)rhu16(acc[ct][r]);
        } else {
            int tt = row0 - bb * T_;        // V transposed: 4 consecutive t
            uint2 pk;
            pk.x = pkbf(acc[ct][0], acc[ct][1]);
            pk.y = pkbf(acc[ct][2], acc[ct][3]);
            *reinterpret_cast<uint2*>(&vtb[((size_t)bb * H_ + h) * T_ + tt]) = pk;
        }
    }
}

// ---------------------------------------------------------------------------
// K2: attention. 512 blocks = (batch &7, 32-row q-tile), 4 waves; wave owns a
// 512-s quarter in 8 chunks of 64 s. Per iteration: 16 direct register loads
// (K waits leave V in flight through S-MFMA/exp), 32 MFMA. LDS: P round-trip
// (wave-private, stride 72) + 4-way split-KV combine epilogue.
// ---------------------------------------------------------------------------
__global__ __launch_bounds__(256, 2) void attn(
        const unsigned short* __restrict__ qb,
        const unsigned short* __restrict__ kb,
        const unsigned short* __restrict__ vtb,
        float* __restrict__ out) {
    __shared__ __align__(16) char smem[25728];
    // main loop: Pw per wave at smem + w*4608 (32 rows x 72 shorts)
    // epilogue (after syncthreads): Osf[3][32][66] f32 (25344B) + Ls[96] f32

    const int t = threadIdx.x, lane = t & 63, w = t >> 6;
    const int l15 = lane & 15, quad = lane >> 4;
    const int bb = blockIdx.x & 7;
    const int q0 = (blockIdx.x >> 3) << 5;
    const size_t kbase = (size_t)bb * T_ * H_;
    unsigned short* Pw = (unsigned short*)(smem + w * 4608);

    // Q B-frags (pre-scaled by 1/32 via Wq), kept in regs for all iterations
    s16x8 qf[2][2];
    #pragma unroll
    for (int rt = 0; rt < 2; rt++)
        #pragma unroll
        for (int ks = 0; ks < 2; ks++)
            qf[rt][ks] = *reinterpret_cast<const s16x8*>(
                &qb[kbase + (size_t)(q0 + rt * 16 + l15) * H_ + ks * 32 + quad * 8]);

    const int sw = w << 9;                 // this wave's s-quarter base
    const unsigned short* kq = kb + kbase + (size_t)(sw + l15) * H_ + quad * 8;
    const unsigned short* vq[4];
    #pragma unroll
    for (int ht = 0; ht < 4; ht++)
        vq[ht] = vtb + ((size_t)bb * H_ + ht * 16 + l15) * T_ + sw + quad * 8;

    f32x4 oacc[2][4];
    #pragma unroll
    for (int rt = 0; rt < 2; rt++)
        #pragma unroll
        for (int ht = 0; ht < 4; ht++)
            #pragma unroll
            for (int j = 0; j < 4; j++) oacc[rt][ht][j] = 0.0f;
    float l_run[2] = {0.0f, 0.0f};
    const f32x4 z4 = {0.0f, 0.0f, 0.0f, 0.0f};

    for (int it = 0; it < 8; it++) {
        // 16 loads issued back-to-back: 8 K-frags then 8 V-frags. Compiler
        // waits per-use: S-MFMA waits only K; V stays in flight until O-MFMA.
        s16x8 kf[4][2], vf[2][4];
        #pragma unroll
        for (int st = 0; st < 4; st++)
            #pragma unroll
            for (int ks = 0; ks < 2; ks++)
                kf[st][ks] = *reinterpret_cast<const s16x8*>(
                    kq + (size_t)(it * 64 + st * 16) * H_ + ks * 32);
        #pragma unroll
        for (int ks2 = 0; ks2 < 2; ks2++)
            #pragma unroll
            for (int ht = 0; ht < 4; ht++)
                vf[ks2][ht] = *reinterpret_cast<const s16x8*>(
                    vq[ht] + it * 64 + ks2 * 32);

        // S^T = K.Q^T : C row = s (quad*4+r), col = q (l15)
        f32x4 sacc[2][4];
        #pragma unroll
        for (int rt = 0; rt < 2; rt++)
            #pragma unroll
            for (int st = 0; st < 4; st++) {
                f32x4 s0v = __builtin_amdgcn_mfma_f32_16x16x32_bf16(
                    kf[st][0], qf[rt][0], z4, 0, 0, 0);
                sacc[rt][st] = __builtin_amdgcn_mfma_f32_16x16x32_bf16(
                    kf[st][1], qf[rt][1], s0v, 0, 0, 0);
            }

        // exp (scores bounded; no max-sub) + packed P write (stride 72)
        #pragma unroll
        for (int rt = 0; rt < 2; rt++) {
            float ls = 0.0f;
            #pragma unroll
            for (int st = 0; st < 4; st++) {
                float p0 = __expf(sacc[rt][st][0]);
                float p1 = __expf(sacc[rt][st][1]);
                float p2 = __expf(sacc[rt][st][2]);
                float p3 = __expf(sacc[rt][st][3]);
                ls += (p0 + p1) + (p2 + p3);
                uint2 pk; pk.x = pkbf(p0, p1); pk.y = pkbf(p2, p3);
                *reinterpret_cast<uint2*>(
                    &Pw[(rt * 16 + l15) * 72 + st * 16 + quad * 4]) = pk;
            }
            l_run[rt] += ls;
        }

        // O += P.V : two 32-s k-steps; P read same-wave LDS (lgkmcnt only)
        #pragma unroll
        for (int rt = 0; rt < 2; rt++)
            #pragma unroll
            for (int ks2 = 0; ks2 < 2; ks2++) {
                s16x8 pf = *reinterpret_cast<const s16x8*>(
                    &Pw[(rt * 16 + l15) * 72 + ks2 * 32 + quad * 8]);
                #pragma unroll
                for (int ht = 0; ht < 4; ht++)
                    oacc[rt][ht] = __builtin_amdgcn_mfma_f32_16x16x32_bf16(
                        pf, vf[ks2][ht], oacc[rt][ht], 0, 0, 0);
            }
    }

    // l: each lane's partial covers its s-quarter rows for q=l15
    #pragma unroll
    for (int rt = 0; rt < 2; rt++) {
        l_run[rt] += __shfl_xor(l_run[rt], 16);
        l_run[rt] += __shfl_xor(l_run[rt], 32);
    }

    // 4-way split-KV combine (plain sums — no max terms)
    __syncthreads();
    float* Osf = (float*)smem;             // [3][32][66]
    float* Ls  = (float*)smem + 3 * 32 * 66;
    if (w > 0) {
        int wi = w - 1;
        #pragma unroll
        for (int rt = 0; rt < 2; rt++) {
            if (quad == 0) Ls[wi * 32 + rt * 16 + l15] = l_run[rt];
            #pragma unroll
            for (int ht = 0; ht < 4; ht++)
                #pragma unroll
                for (int r = 0; r < 4; r++)
                    Osf[wi * 2112 + (rt * 16 + quad * 4 + r) * 66 + ht * 16 + l15] = oacc[rt][ht][r];
        }
    }
    __syncthreads();
    if (w == 0) {
        #pragma unroll
        for (int rt = 0; rt < 2; rt++)
            #pragma unroll
            for (int r = 0; r < 4; r++) {
                int row = rt * 16 + quad * 4 + r;
                float lt = __shfl(l_run[rt], quad * 4 + r)
                         + Ls[0 * 32 + row] + Ls[1 * 32 + row] + Ls[2 * 32 + row];
                float inv = 1.0f / lt;
                #pragma unroll
                for (int ht = 0; ht < 4; ht++) {
                    float o = oacc[rt][ht][r]
                            + Osf[0 * 2112 + row * 66 + ht * 16 + l15]
                            + Osf[1 * 2112 + row * 66 + ht * 16 + l15]
                            + Osf[2 * 2112 + row * 66 + ht * 16 + l15];
                    out[kbase + (size_t)(q0 + row) * H_ + ht * 16 + l15] = o * inv;
                }
            }
    }
}

extern "C" void kernel_launch(void* const* d_in, const int* in_sizes, int n_in,
                              void* d_out, int out_size, void* d_ws, size_t ws_size,
                              hipStream_t stream) {
    const float* x  = (const float*)d_in[0];
    const float* Wk = (const float*)d_in[1];
    const float* Wq = (const float*)d_in[2];
    const float* Wv = (const float*)d_in[3];

    unsigned short* kb  = (unsigned short*)d_ws;               // 2 MB
    unsigned short* qbf = kb  + (size_t)B_ * T_ * H_;          // 2 MB
    unsigned short* vtb = qbf + (size_t)B_ * T_ * H_;          // 2 MB
    unsigned short* Wt  = (unsigned short*)d_out;              // 384 KB scratch

    wconv<<<48,  256, 0, stream>>>(Wk, Wq, Wv, Wt);
    qkv  <<<512, 512, 0, stream>>>(x, Wt, kb, qbf, vtb);
    attn <<<512, 256, 0, stream>>>(qbf, kb, vtb, (float*)d_out);
}

// Round 9
// 154.450 us; speedup vs baseline: 1.0632x; 1.0632x over previous
//
#include <hip/hip_runtime.h>
#include <stdint.h>

// Head: x[8,2048,1024] fp32; Wk/Wq/Wv [1024,64] fp32 -> out [8,2048,64] fp32
// R15 (resubmit — R8 bench was an acquisition timeout, no data).
// qkv = R4/R13 sync structure (block-coop global_load_lds dbuf, one
// syncthreads/chunk — proven 40us; R14's counted-vmcnt was WORSE, 52us,
// refuting the drain theory) with the TILE doubled: 64 rows x 192 cols,
// 256 blocks x 512 thr. W-staging is the dominant staged traffic (each
// block stages ALL 384KB of Wt): 512x384KB=192MB at 32-row tiles ->
// 256x384KB=96MB at 64-row tiles, and per-barrier compute doubles (12
// MFMA/wave/chunk, acc[2][3] = original R4 layout). LDS 80KB dbuf.
// wconv + attn unchanged (R9 best).

#define B_ 8
#define T_ 2048
#define C_ 1024
#define H_ 64

typedef float f32x4 __attribute__((ext_vector_type(4)));
typedef short s16x8 __attribute__((ext_vector_type(8)));

__device__ __forceinline__ unsigned int rhu16(float f) {
    return (__float_as_uint(f) + 0x8000u) >> 16;
}
__device__ __forceinline__ unsigned int pkbf(float lo, float hi) {
    unsigned int a = __float_as_uint(lo) + 0x8000u;
    unsigned int b = __float_as_uint(hi) + 0x8000u;
    return __builtin_amdgcn_perm(b, a, 0x07060302u);   // bytes [b3 b2 a3 a2]
}
// async global->LDS, 16B per lane; LDS dest = wave-uniform base + lane*16
__device__ __forceinline__ void ld_lds16(const void* g, void* l) {
    __builtin_amdgcn_global_load_lds(
        (const __attribute__((address_space(1))) unsigned int*)g,
        (__attribute__((address_space(3))) unsigned int*)l, 16, 0, 0);
}

// ---------------------------------------------------------------------------
// K0: 48 blocks = 3 mats x 16 c-groups of 64. Coalesced read, LDS transpose
// (stride 65), coalesced bf16 write. Wq pre-scaled by 1/32 (C^-0.5).
// ---------------------------------------------------------------------------
__global__ __launch_bounds__(256) void wconv(const float* __restrict__ Wk,
        const float* __restrict__ Wq, const float* __restrict__ Wv,
        unsigned short* __restrict__ Wt) {
    __shared__ float ls[64 * 65];
    const int bx = blockIdx.x, t = threadIdx.x;
    const int mat = bx >> 4, c0 = (bx & 15) << 6;
    const float* W = (mat == 0) ? Wk : ((mat == 1) ? Wq : Wv);
    const float sc = (mat == 1) ? 0.03125f : 1.0f;
    #pragma unroll
    for (int k = 0; k < 4; k++) {
        int i = t + (k << 8);
        int cr = i >> 4, hq = (i & 15) << 2;
        float4 v = *reinterpret_cast<const float4*>(&W[(size_t)(c0 + cr) * H_ + hq]);
        ls[cr * 65 + hq + 0] = v.x; ls[cr * 65 + hq + 1] = v.y;
        ls[cr * 65 + hq + 2] = v.z; ls[cr * 65 + hq + 3] = v.w;
    }
    __syncthreads();
    #pragma unroll
    for (int k = 0; k < 4; k++) {
        int i = t + (k << 8);
        int h = i >> 4, cq = (i & 15) << 2;
        float a = ls[(cq + 0) * 65 + h] * sc, b = ls[(cq + 1) * 65 + h] * sc;
        float c = ls[(cq + 2) * 65 + h] * sc, d = ls[(cq + 3) * 65 + h] * sc;
        uint2 o; o.x = pkbf(a, b); o.y = pkbf(c, d);
        *reinterpret_cast<uint2*>(&Wt[(size_t)(mat * 64 + h) * C_ + c0 + cq]) = o;
    }
}

// ---------------------------------------------------------------------------
// K1: QKV projection — 64-row tiles. 256 blocks x 512 thr; block = 64 rows
// x 192 cols; wave (wr=w>>2, colb=(w&3)*48) owns 32 rows x 48 cols =
// acc[2][3]. Per 64-k chunk per wave: 2 x-stages + 3 W-stages
// (global_load_lds 16B), ds_read frags, pack, 12 MFMA, 1 barrier.
// LDS dbuf 2 x (16KB x + 24KB W) = 80KB.
// ---------------------------------------------------------------------------
__global__ __launch_bounds__(512) __attribute__((amdgpu_waves_per_eu(2)))
void qkv(const float* __restrict__ x,
        const unsigned short* __restrict__ Wt,
        unsigned short* __restrict__ kb, unsigned short* __restrict__ qb,
        unsigned short* __restrict__ vtb) {
    __shared__ __align__(16) char smem[81920];   // 2 bufs x (16KB x | 24KB W)
    const int t = threadIdx.x, lane = t & 63, w = t >> 6;   // w in 0..7
    const int l15 = lane & 15, quad = lane >> 4;
    const int bx = blockIdx.x;
    const int bb = bx >> 5;                 // batch
    const int mt = bx & 31;                 // 64-row tile within batch
    const int m0 = bb * T_ + mt * 64;
    const int wr = w >> 2;                  // 32-row half of the 64-row tile
    const int colb = (w & 3) * 48;          // 48-col strip

    // per-wave async shares: 2 x-instrs (id = w*2+n), 3 W-instrs (g = w*3+n).
    // x LDS layout [rg][j][quad][l15] @ id*1024+lane*16 (id = rg*4+j, rg =
    // 16-row group 0..3, j = k-sixteenth); W layout [g][k8][col&7] @ 16384.
    size_t xg[2]; int xl[2];
    #pragma unroll
    for (int n = 0; n < 2; n++) {
        int id = w * 2 + n, rg = id >> 2, j = id & 3;
        xg[n] = (size_t)(m0 + rg * 16 + l15) * C_ + j * 16 + quad * 4;
        xl[n] = id * 1024 + lane * 16;
    }
    size_t wg[3]; int wl[3];
    #pragma unroll
    for (int n = 0; n < 3; n++) {
        int g = w * 3 + n;
        wg[n] = (size_t)(g * 8 + (lane & 7)) * C_ + (lane >> 3) * 8;
        wl[n] = 16384 + g * 1024 + lane * 16;
    }

    // prologue: stage chunk 0
    #pragma unroll
    for (int n = 0; n < 2; n++) ld_lds16(x + xg[n], smem + xl[n]);
    #pragma unroll
    for (int n = 0; n < 3; n++) ld_lds16(Wt + wg[n], smem + wl[n]);
    __syncthreads();

    f32x4 acc[2][3];
    #pragma unroll
    for (int rt = 0; rt < 2; rt++)
        #pragma unroll
        for (int ct = 0; ct < 3; ct++)
            #pragma unroll
            for (int j = 0; j < 4; j++) acc[rt][ct][j] = 0.0f;

    #pragma unroll
    for (int i = 0; i < 16; i++) {
        const int cb = i & 1;
        const char* cur = smem + cb * 40960;
        const float* xc = (const float*)cur;
        const unsigned short* wcp = (const unsigned short*)(cur + 16384);

        // frag reads from LDS (no outstanding vmcnt here: drained at barrier)
        float4 xr[2][2][2];
        #pragma unroll
        for (int rt = 0; rt < 2; rt++)
            #pragma unroll
            for (int ks = 0; ks < 2; ks++)
                #pragma unroll
                for (int h = 0; h < 2; h++) {
                    int c = ks * 32 + quad * 8 + h * 4;
                    int j = c >> 4, u = (c & 15) >> 2;
                    int rg = wr * 2 + rt;
                    xr[rt][ks][h] = *reinterpret_cast<const float4*>(
                        xc + (rg * 4 + j) * 256 + u * 64 + l15 * 4);
                }
        s16x8 wfr[3][2];
        #pragma unroll
        for (int ct = 0; ct < 3; ct++)
            #pragma unroll
            for (int ks = 0; ks < 2; ks++) {
                int col = colb + ct * 16 + l15;
                wfr[ct][ks] = *reinterpret_cast<const s16x8*>(
                    wcp + (col >> 3) * 512 + ((4 * ks + quad) * 8 + (col & 7)) * 8);
            }

        // prefetch chunk i+1 into the other buffer (async, overlaps compute)
        if (i < 15) {
            const int c1 = (i + 1) * 64;
            char* nxt = smem + (cb ^ 1) * 40960;
            #pragma unroll
            for (int n = 0; n < 2; n++) ld_lds16(x + xg[n] + c1, nxt + xl[n]);
            #pragma unroll
            for (int n = 0; n < 3; n++) ld_lds16(Wt + wg[n] + c1, nxt + wl[n]);
        }

        // pack fp32 -> bf16 A-frags and MFMA
        s16x8 af[2][2];
        #pragma unroll
        for (int rt = 0; rt < 2; rt++)
            #pragma unroll
            for (int ks = 0; ks < 2; ks++) {
                const float4 a = xr[rt][ks][0], b = xr[rt][ks][1];
                uint4 pk;
                pk.x = pkbf(a.x, a.y); pk.y = pkbf(a.z, a.w);
                pk.z = pkbf(b.x, b.y); pk.w = pkbf(b.z, b.w);
                af[rt][ks] = *reinterpret_cast<s16x8*>(&pk);
            }
        #pragma unroll
        for (int ks = 0; ks < 2; ks++)
            #pragma unroll
            for (int rt = 0; rt < 2; rt++)
                #pragma unroll
                for (int ct = 0; ct < 3; ct++)
                    acc[rt][ct] = __builtin_amdgcn_mfma_f32_16x16x32_bf16(
                        af[rt][ks], wfr[ct][ks], acc[rt][ct], 0, 0, 0);
        __syncthreads();   // waves' asyncs drained (compiler vmcnt(0)) + swap
    }

    // epilogue: C row = quad*4+reg, col = l15
    #pragma unroll
    for (int ct = 0; ct < 3; ct++) {
        int cbv = colb + ct * 16;
        int sel = cbv >> 6;                 // 0=K 1=Q 2=V, wave-uniform
        int h = (cbv & 63) + l15;
        #pragma unroll
        for (int rt = 0; rt < 2; rt++) {
            int row0 = m0 + (wr * 2 + rt) * 16 + quad * 4;
            if (sel < 2) {
                unsigned short* dst = sel ? qb : kb;
                #pragma unroll
                for (int r = 0; r < 4; r++)
                    dst[(size_t)(row0 + r) * H_ + h] = (unsigned short)rhu16(acc[rt][ct][r]);
            } else {
                int tt = row0 - bb * T_;    // V transposed: 4 consecutive t
                uint2 pk;
                pk.x = pkbf(acc[rt][ct][0], acc[rt][ct][1]);
                pk.y = pkbf(acc[rt][ct][2], acc[rt][ct][3]);
                *reinterpret_cast<uint2*>(&vtb[((size_t)bb * H_ + h) * T_ + tt]) = pk;
            }
        }
    }
}

// ---------------------------------------------------------------------------
// K2: attention. 512 blocks = (batch &7, 32-row q-tile), 4 waves; wave owns a
// 512-s quarter in 8 chunks of 64 s. Per iteration: 16 direct register loads
// (K waits leave V in flight through S-MFMA/exp), 32 MFMA. LDS: P round-trip
// (wave-private, stride 72) + 4-way split-KV combine epilogue.
// ---------------------------------------------------------------------------
__global__ __launch_bounds__(256, 2) void attn(
        const unsigned short* __restrict__ qb,
        const unsigned short* __restrict__ kb,
        const unsigned short* __restrict__ vtb,
        float* __restrict__ out) {
    __shared__ __align__(16) char smem[25728];
    // main loop: Pw per wave at smem + w*4608 (32 rows x 72 shorts)
    // epilogue (after syncthreads): Osf[3][32][66] f32 (25344B) + Ls[96] f32

    const int t = threadIdx.x, lane = t & 63, w = t >> 6;
    const int l15 = lane & 15, quad = lane >> 4;
    const int bb = blockIdx.x & 7;
    const int q0 = (blockIdx.x >> 3) << 5;
    const size_t kbase = (size_t)bb * T_ * H_;
    unsigned short* Pw = (unsigned short*)(smem + w * 4608);

    // Q B-frags (pre-scaled by 1/32 via Wq), kept in regs for all iterations
    s16x8 qf[2][2];
    #pragma unroll
    for (int rt = 0; rt < 2; rt++)
        #pragma unroll
        for (int ks = 0; ks < 2; ks++)
            qf[rt][ks] = *reinterpret_cast<const s16x8*>(
                &qb[kbase + (size_t)(q0 + rt * 16 + l15) * H_ + ks * 32 + quad * 8]);

    const int sw = w << 9;                 // this wave's s-quarter base
    const unsigned short* kq = kb + kbase + (size_t)(sw + l15) * H_ + quad * 8;
    const unsigned short* vq[4];
    #pragma unroll
    for (int ht = 0; ht < 4; ht++)
        vq[ht] = vtb + ((size_t)bb * H_ + ht * 16 + l15) * T_ + sw + quad * 8;

    f32x4 oacc[2][4];
    #pragma unroll
    for (int rt = 0; rt < 2; rt++)
        #pragma unroll
        for (int ht = 0; ht < 4; ht++)
            #pragma unroll
            for (int j = 0; j < 4; j++) oacc[rt][ht][j] = 0.0f;
    float l_run[2] = {0.0f, 0.0f};
    const f32x4 z4 = {0.0f, 0.0f, 0.0f, 0.0f};

    for (int it = 0; it < 8; it++) {
        // 16 loads issued back-to-back: 8 K-frags then 8 V-frags. Compiler
        // waits per-use: S-MFMA waits only K; V stays in flight until O-MFMA.
        s16x8 kf[4][2], vf[2][4];
        #pragma unroll
        for (int st = 0; st < 4; st++)
            #pragma unroll
            for (int ks = 0; ks < 2; ks++)
                kf[st][ks] = *reinterpret_cast<const s16x8*>(
                    kq + (size_t)(it * 64 + st * 16) * H_ + ks * 32);
        #pragma unroll
        for (int ks2 = 0; ks2 < 2; ks2++)
            #pragma unroll
            for (int ht = 0; ht < 4; ht++)
                vf[ks2][ht] = *reinterpret_cast<const s16x8*>(
                    vq[ht] + it * 64 + ks2 * 32);

        // S^T = K.Q^T : C row = s (quad*4+r), col = q (l15)
        f32x4 sacc[2][4];
        #pragma unroll
        for (int rt = 0; rt < 2; rt++)
            #pragma unroll
            for (int st = 0; st < 4; st++) {
                f32x4 s0v = __builtin_amdgcn_mfma_f32_16x16x32_bf16(
                    kf[st][0], qf[rt][0], z4, 0, 0, 0);
                sacc[rt][st] = __builtin_amdgcn_mfma_f32_16x16x32_bf16(
                    kf[st][1], qf[rt][1], s0v, 0, 0, 0);
            }

        // exp (scores bounded; no max-sub) + packed P write (stride 72)
        #pragma unroll
        for (int rt = 0; rt < 2; rt++) {
            float ls = 0.0f;
            #pragma unroll
            for (int st = 0; st < 4; st++) {
                float p0 = __expf(sacc[rt][st][0]);
                float p1 = __expf(sacc[rt][st][1]);
                float p2 = __expf(sacc[rt][st][2]);
                float p3 = __expf(sacc[rt][st][3]);
                ls += (p0 + p1) + (p2 + p3);
                uint2 pk; pk.x = pkbf(p0, p1); pk.y = pkbf(p2, p3);
                *reinterpret_cast<uint2*>(
                    &Pw[(rt * 16 + l15) * 72 + st * 16 + quad * 4]) = pk;
            }
            l_run[rt] += ls;
        }

        // O += P.V : two 32-s k-steps; P read same-wave LDS (lgkmcnt only)
        #pragma unroll
        for (int rt = 0; rt < 2; rt++)
            #pragma unroll
            for (int ks2 = 0; ks2 < 2; ks2++) {
                s16x8 pf = *reinterpret_cast<const s16x8*>(
                    &Pw[(rt * 16 + l15) * 72 + ks2 * 32 + quad * 8]);
                #pragma unroll
                for (int ht = 0; ht < 4; ht++)
                    oacc[rt][ht] = __builtin_amdgcn_mfma_f32_16x16x32_bf16(
                        pf, vf[ks2][ht], oacc[rt][ht], 0, 0, 0);
            }
    }

    // l: each lane's partial covers its s-quarter rows for q=l15
    #pragma unroll
    for (int rt = 0; rt < 2; rt++) {
        l_run[rt] += __shfl_xor(l_run[rt], 16);
        l_run[rt] += __shfl_xor(l_run[rt], 32);
    }

    // 4-way split-KV combine (plain sums — no max terms)
    __syncthreads();
    float* Osf = (float*)smem;             // [3][32][66]
    float* Ls  = (float*)smem + 3 * 32 * 66;
    if (w > 0) {
        int wi = w - 1;
        #pragma unroll
        for (int rt = 0; rt < 2; rt++) {
            if (quad == 0) Ls[wi * 32 + rt * 16 + l15] = l_run[rt];
            #pragma unroll
            for (int ht = 0; ht < 4; ht++)
                #pragma unroll
                for (int r = 0; r < 4; r++)
                    Osf[wi * 2112 + (rt * 16 + quad * 4 + r) * 66 + ht * 16 + l15] = oacc[rt][ht][r];
        }
    }
    __syncthreads();
    if (w == 0) {
        #pragma unroll
        for (int rt = 0; rt < 2; rt++)
            #pragma unroll
            for (int r = 0; r < 4; r++) {
                int row = rt * 16 + quad * 4 + r;
                float lt = __shfl(l_run[rt], quad * 4 + r)
                         + Ls[0 * 32 + row] + Ls[1 * 32 + row] + Ls[2 * 32 + row];
                float inv = 1.0f / lt;
                #pragma unroll
                for (int ht = 0; ht < 4; ht++) {
                    float o = oacc[rt][ht][r]
                            + Osf[0 * 2112 + row * 66 + ht * 16 + l15]
                            + Osf[1 * 2112 + row * 66 + ht * 16 + l15]
                            + Osf[2 * 2112 + row * 66 + ht * 16 + l15];
                    out[kbase + (size_t)(q0 + row) * H_ + ht * 16 + l15] = o * inv;
                }
            }
    }
}

extern "C" void kernel_launch(void* const* d_in, const int* in_sizes, int n_in,
                              void* d_out, int out_size, void* d_ws, size_t ws_size,
                              hipStream_t stream) {
    const float* x  = (const float*)d_in[0];
    const float* Wk = (const float*)d_in[1];
    const float* Wq = (const float*)d_in[2];
    const float* Wv = (const float*)d_in[3];

    unsigned short* kb  = (unsigned short*)d_ws;               // 2 MB
    unsigned short* qbf = kb  + (size_t)B_ * T_ * H_;          // 2 MB
    unsigned short* vtb = qbf + (size_t)B_ * T_ * H_;          // 2 MB
    unsigned short* Wt  = (unsigned short*)d_out;              // 384 KB scratch

    wconv<<<48,  256, 0, stream>>>(Wk, Wq, Wv, Wt);
    qkv  <<<256, 512, 0, stream>>>(x, Wt, kb, qbf, vtb);
    attn <<<512, 256, 0, stream>>>(qbf, kb, vtb, (float*)d_out);
}